// Round 9
// baseline (1931.913 us; speedup 1.0000x reference)
//
#include <hip/hip_runtime.h>

#define N_NODES 100000
#define N_EDGES 3200000
#define IN_C 602
#define KPAD 608
#define NT 19           // KPAD/32 k-tiles
#define HID_C 256
#define OUTC 41
#define HSTR 64         // bf16 h0 row stride (128 B)
#define K_ITERS 10
#define NBUK 391        // ceil(N_NODES/256) buckets for binned CSC build

typedef __attribute__((ext_vector_type(8))) short bf16x8;
typedef __attribute__((ext_vector_type(4))) float f32x4;
typedef __attribute__((ext_vector_type(2))) float f32x2;

static __device__ __forceinline__ unsigned short f2bf(float f) {
  unsigned u = __float_as_uint(f);
  u += 0x7fffu + ((u >> 16) & 1u);
  return (unsigned short)(u >> 16);
}
static __device__ __forceinline__ float bf2f(unsigned short h) {
  return __uint_as_float(((unsigned)h) << 16);
}
static __device__ __forceinline__ float bflo(unsigned u) {
  return __uint_as_float(u << 16);
}
static __device__ __forceinline__ float bfhi(unsigned u) {
  return __uint_as_float(u & 0xffff0000u);
}

// ---------------- degree ----------------
__global__ __launch_bounds__(256) void deg_kernel(const int* __restrict__ col,
                                                  unsigned* __restrict__ deg) {
  int e = blockIdx.x * 256 + threadIdx.x;
  if (e < N_EDGES) atomicAdd(&deg[col[e]], 1u);
}

__global__ __launch_bounds__(256) void dinv_kernel(const unsigned* __restrict__ deg,
                                                   float* __restrict__ dinv) {
  int i = blockIdx.x * 256 + threadIdx.x;
  if (i < N_NODES) dinv[i] = rsqrtf((float)(deg[i] + 1u));
}

// ---------------- bucket histogram (LDS-staged) ----------------
__global__ __launch_bounds__(256) void bhist_kernel(const int* __restrict__ col,
                                                    unsigned* __restrict__ bhist) {
  __shared__ unsigned lh[NBUK + 1];
  for (int i = threadIdx.x; i <= NBUK; i += 256) lh[i] = 0;
  __syncthreads();
  for (int e = blockIdx.x * 256 + threadIdx.x; e < N_EDGES; e += gridDim.x * 256)
    atomicAdd(&lh[col[e] >> 8], 1u);
  __syncthreads();
  for (int i = threadIdx.x; i < NBUK; i += 256)
    if (lh[i]) atomicAdd(&bhist[i], lh[i]);
}

// ---------------- 391-entry exclusive scan (1 block) ----------------
__global__ __launch_bounds__(512) void scanb_kernel(const unsigned* __restrict__ bhist,
                                                    unsigned* __restrict__ bbase2) {
  __shared__ unsigned wsum[8];
  __shared__ unsigned wbase[8];
  const int t = threadIdx.x, lane = t & 63, w = t >> 6;
  unsigned v = (t < NBUK) ? bhist[t] : 0u;
  unsigned inc = v;
  for (int d = 1; d < 64; d <<= 1) {
    unsigned x = (unsigned)__shfl_up((int)inc, d);
    if (lane >= d) inc += x;
  }
  if (lane == 63) wsum[w] = inc;
  __syncthreads();
  if (t == 0) {
    unsigned run = 0;
    for (int i = 0; i < 8; ++i) { unsigned s = wsum[i]; wbase[i] = run; run += s; }
  }
  __syncthreads();
  if (t < NBUK) bbase2[t] = wbase[w] + inc - v;
}

// ---------------- bin pass: COO -> bucket-grouped packed records ----------
// record = (c & 255) << 17 | r   (r < 2^17, 4 bytes)
__global__ __launch_bounds__(256) void bin_kernel(const int* __restrict__ row,
                                                  const int* __restrict__ col,
                                                  const unsigned* __restrict__ bbase2,
                                                  unsigned* __restrict__ gcur,
                                                  unsigned* __restrict__ binned) {
  int e = blockIdx.x * 256 + threadIdx.x;
  if (e >= N_EDGES) return;
  int r = row[e], c = col[e];
  int b = c >> 8;
  unsigned pos = atomicAdd(&gcur[b], 1u);
  binned[bbase2[b] + pos] = (((unsigned)(c & 255)) << 17) | (unsigned)r;
}

// ---------------- place pass: bucket-grouped -> exact CSC (rec4 = r) ------
__global__ __launch_bounds__(256) void place_kernel(const unsigned* __restrict__ binned,
                                                    const unsigned* __restrict__ bbase2,
                                                    const unsigned* __restrict__ bhist,
                                                    const unsigned* __restrict__ offs,
                                                    unsigned* __restrict__ cursor,
                                                    unsigned* __restrict__ rec4) {
  const int b = blockIdx.x;
  const unsigned s = bbase2[b];
  const unsigned cnt = bhist[b];
  for (unsigned i = threadIdx.x; i < cnt; i += 256) {
    unsigned v = binned[s + i];
    int c = (b << 8) | (int)(v >> 17);
    unsigned r = v & 0x1FFFFu;
    unsigned pos = offs[c] + atomicAdd(&cursor[c], 1u);
    rec4[pos] = r;
  }
}

// ------- W1 bf16 (nearest) in fragment-linear layout [t][n][g][8] --------
__global__ __launch_bounds__(256) void wprep1_kernel(const float* __restrict__ W1,
                                                     unsigned short* __restrict__ Whf) {
  int idx = blockIdx.x * 256 + threadIdx.x;
  if (idx >= HID_C * KPAD) return;
  int n = idx / KPAD, k = idx % KPAD;
  float v = (k < IN_C) ? W1[n * IN_C + k] : 0.f;
  int t = k >> 5, g = (k >> 3) & 3, j = k & 7;
  Whf[(size_t)t * 8192 + (((n << 2) + g) << 3) + j] = f2bf(v);
}

// ------- W2 hi/lo split, fragment-linear [ks][n(48)][g][8] ---------------
__global__ __launch_bounds__(256) void wprep2_kernel(const float* __restrict__ W2,
                                                     unsigned short* __restrict__ W2hf,
                                                     unsigned short* __restrict__ W2lf) {
  int idx = blockIdx.x * 256 + threadIdx.x;
  if (idx >= 48 * HID_C) return;
  int n = idx >> 8, k = idx & 255;
  float v = (n < OUTC) ? W2[n * HID_C + k] : 0.f;
  unsigned short hi = f2bf(v);
  int ks = k >> 5, g = (k >> 3) & 3, j = k & 7;
  size_t dst = (size_t)ks * 1536 + (((n << 2) + g) << 3) + j;
  W2hf[dst] = hi;
  W2lf[dst] = f2bf(v - bf2f(hi));
}

// ---------------- GEMM1: h1 = relu(x @ W1^T + b1), bf16 out --------------
__global__ __launch_bounds__(256, 3) void gemm1_kernel(
    const float* __restrict__ x,
    const unsigned short* __restrict__ Whf,
    const float* __restrict__ b1,
    unsigned short* __restrict__ h1g) {
  __shared__ __align__(16) float4 xt[3 * 512];        // 24 KB; reused as h1t
  unsigned short* h1t = (unsigned short*)xt;          // [32][264] in epilogue

  const int tid = threadIdx.x;
  const int lane = tid & 63;
  const int w = tid >> 6;
  const int r0 = blockIdx.x * 64;
  const int fr = lane & 15;
  const int g = lane >> 4;

  const int srow = tid >> 3;
  const int sc = tid & 7;
  int gr0 = r0 + srow;       if (gr0 >= N_NODES) gr0 = N_NODES - 1;
  int gr1 = r0 + srow + 32;  if (gr1 >= N_NODES) gr1 = N_NODES - 1;
  const float* xp0 = x + (size_t)gr0 * IN_C;
  const float* xp1 = x + (size_t)gr1 * IN_C;
  const int ws0 = srow * 8 + (sc ^ (srow & 7));
  const int ws1 = (srow + 32) * 8 + (sc ^ (srow & 7));

  f32x4 acc[4][4];
  {
    const int bcol0 = (w << 6) + fr;
#pragma unroll
    for (int s = 0; s < 4; ++s) {
      float bv = b1[bcol0 + s * 16];
#pragma unroll
      for (int mi = 0; mi < 4; ++mi) acc[mi][s] = (f32x4){bv, bv, bv, bv};
    }
  }

  float4 pA0, pA1, pB0, pB1;
  bf16x8 bhv[2][4];

#define STAGE_LOAD0(T)                                                     \
  { const int kb = (T) * 32 + sc * 4;                                      \
    if ((T) < NT - 1) { pA0 = *(const float4*)(xp0 + kb);                  \
                        pA1 = *(const float4*)(xp1 + kb); }                \
    else { float t0[4], t1[4];                                             \
      _Pragma("unroll") for (int j = 0; j < 4; ++j) { int k = kb + j;      \
        t0[j] = (k < IN_C) ? xp0[k] : 0.f; t1[j] = (k < IN_C) ? xp1[k] : 0.f; } \
      pA0 = (float4){t0[0], t0[1], t0[2], t0[3]};                          \
      pA1 = (float4){t1[0], t1[1], t1[2], t1[3]}; } }

#define STAGE_LOAD1(T)                                                     \
  { const int kb = (T) * 32 + sc * 4;                                      \
    if ((T) < NT - 1) { pB0 = *(const float4*)(xp0 + kb);                  \
                        pB1 = *(const float4*)(xp1 + kb); }                \
    else { float t0[4], t1[4];                                             \
      _Pragma("unroll") for (int j = 0; j < 4; ++j) { int k = kb + j;      \
        t0[j] = (k < IN_C) ? xp0[k] : 0.f; t1[j] = (k < IN_C) ? xp1[k] : 0.f; } \
      pB0 = (float4){t0[0], t0[1], t0[2], t0[3]};                          \
      pB1 = (float4){t1[0], t1[1], t1[2], t1[3]}; } }

#define STAGE_WRITE0(BW) { xt[(BW) * 512 + ws0] = pA0; xt[(BW) * 512 + ws1] = pA1; }
#define STAGE_WRITE1(BW) { xt[(BW) * 512 + ws0] = pB0; xt[(BW) * 512 + ws1] = pB1; }

#define LOADB(T, PAR)                                                      \
  { const size_t tb = (size_t)(T) * 8192;                                  \
    _Pragma("unroll") for (int s = 0; s < 4; ++s) {                        \
      const int n4 = (((w << 6) + s * 16 + fr) << 2) + g;                  \
      bhv[PAR][s] = *(const bf16x8*)(Whf + tb + n4 * 8);                   \
    } }

#define COMPUTE(BR, PAR)                                                   \
  { _Pragma("unroll") for (int mi = 0; mi < 4; ++mi) {                     \
      const int rr = mi * 16 + fr;                                         \
      float4 pa = xt[(BR) * 512 + rr * 8 + ((2 * g) ^ (fr & 7))];          \
      float4 pb = xt[(BR) * 512 + rr * 8 + ((2 * g + 1) ^ (fr & 7))];      \
      union { unsigned u[4]; bf16x8 v; } hh, ll;                           \
      asm("v_cvt_pk_bf16_f32 %0, %1, %2" : "=v"(hh.u[0]) : "v"(pa.x), "v"(pa.y)); \
      asm("v_cvt_pk_bf16_f32 %0, %1, %2" : "=v"(hh.u[1]) : "v"(pa.z), "v"(pa.w)); \
      asm("v_cvt_pk_bf16_f32 %0, %1, %2" : "=v"(hh.u[2]) : "v"(pb.x), "v"(pb.y)); \
      asm("v_cvt_pk_bf16_f32 %0, %1, %2" : "=v"(hh.u[3]) : "v"(pb.z), "v"(pb.w)); \
      float l0 = pa.x - bflo(hh.u[0]), l1 = pa.y - bfhi(hh.u[0]);          \
      float l2 = pa.z - bflo(hh.u[1]), l3 = pa.w - bfhi(hh.u[1]);          \
      float l4 = pb.x - bflo(hh.u[2]), l5 = pb.y - bfhi(hh.u[2]);          \
      float l6 = pb.z - bflo(hh.u[3]), l7 = pb.w - bfhi(hh.u[3]);          \
      asm("v_cvt_pk_bf16_f32 %0, %1, %2" : "=v"(ll.u[0]) : "v"(l0), "v"(l1)); \
      asm("v_cvt_pk_bf16_f32 %0, %1, %2" : "=v"(ll.u[1]) : "v"(l2), "v"(l3)); \
      asm("v_cvt_pk_bf16_f32 %0, %1, %2" : "=v"(ll.u[2]) : "v"(l4), "v"(l5)); \
      asm("v_cvt_pk_bf16_f32 %0, %1, %2" : "=v"(ll.u[3]) : "v"(l6), "v"(l7)); \
      _Pragma("unroll") for (int s = 0; s < 4; ++s) {                      \
        acc[mi][s] = __builtin_amdgcn_mfma_f32_16x16x32_bf16(              \
            hh.v, bhv[PAR][s], acc[mi][s], 0, 0, 0);                       \
        acc[mi][s] = __builtin_amdgcn_mfma_f32_16x16x32_bf16(              \
            ll.v, bhv[PAR][s], acc[mi][s], 0, 0, 0);                       \
      } } }

#define BODY(T, PAR)                                                       \
  { int bW = bR + 1; if (bW == 3) bW = 0;                                  \
    if ((T) + 1 < NT) {                                                    \
      if ((PAR) == 0) STAGE_WRITE1(bW) else STAGE_WRITE0(bW);              \
      if ((T) + 3 < NT) { if ((PAR) == 0) STAGE_LOAD1((T) + 3)             \
                          else STAGE_LOAD0((T) + 3); }                     \
      LOADB((T) + 1, (PAR) ^ 1);                                           \
    }                                                                      \
    COMPUTE(bR, PAR);                                                      \
    __syncthreads();                                                       \
    bR = bW; }

  STAGE_LOAD0(0);
  STAGE_WRITE0(0);
  STAGE_LOAD1(1);
  STAGE_LOAD0(2);
  LOADB(0, 0);
  __syncthreads();

  int bR = 0;
  for (int t = 0; t + 1 < NT; t += 2) {
    BODY(t, 0);
    BODY(t + 1, 1);
  }
  BODY(NT - 1, 0);  // NT odd: tail tile, parity 0

  // epilogue: coalesced h1 store via 2 LDS chunks of 32 rows
#pragma unroll
  for (int ch = 0; ch < 2; ++ch) {
#pragma unroll
    for (int mi2 = 0; mi2 < 2; ++mi2) {
      const int mi = ch * 2 + mi2;
#pragma unroll
      for (int s = 0; s < 4; ++s)
#pragma unroll
        for (int q = 0; q < 4; ++q) {
          int rr = mi2 * 16 + (g << 2) + q;
          int cc = (w << 6) + s * 16 + fr;
          h1t[rr * 264 + cc] = f2bf(fmaxf(acc[mi][s][q], 0.f));
        }
    }
    __syncthreads();
    {
      const int row = tid >> 3, seg = tid & 7;
      const int gr = r0 + ch * 32 + row;
      if (gr < N_NODES) {
        const uint4* src = (const uint4*)&h1t[row * 264 + seg * 32];
        uint4* dst = (uint4*)(h1g + (size_t)gr * 256 + seg * 32);
        dst[0] = src[0];
        dst[1] = src[1];
        dst[2] = src[2];
        dst[3] = src[3];
      }
    }
    __syncthreads();
  }
}

// ------- GEMM2 + L2 norm: H0 = normalize(h1 @ W2^T + b2), bf16 out -------
__global__ __launch_bounds__(256) void gemm2_kernel(
    const unsigned short* __restrict__ h1g,
    const unsigned short* __restrict__ W2hf,
    const unsigned short* __restrict__ W2lf,
    const float* __restrict__ b2,
    unsigned short* __restrict__ H0) {
  const int tid = threadIdx.x;
  const int lane = tid & 63;
  const int w = tid >> 6;
  const int fr = lane & 15;
  const int g = lane >> 4;
  const int wr0 = blockIdx.x * 64 + w * 16;

  f32x4 acc[3];
#pragma unroll
  for (int s = 0; s < 3; ++s) {
    int c = s * 16 + fr;
    float bv = (c < OUTC) ? b2[c] : 0.f;
    acc[s] = (f32x4){bv, bv, bv, bv};
  }

  int ar = wr0 + fr;
  if (ar >= N_NODES) ar = N_NODES - 1;
  const unsigned short* ap = h1g + (size_t)ar * 256 + g * 8;

#pragma unroll
  for (int ks = 0; ks < 8; ++ks) {
    bf16x8 a = *(const bf16x8*)(ap + ks * 32);
#pragma unroll
    for (int s = 0; s < 3; ++s) {
      const int n4 = (((s * 16 + fr) << 2) + g) << 3;
      bf16x8 bh = *(const bf16x8*)(W2hf + (size_t)ks * 1536 + n4);
      bf16x8 bl = *(const bf16x8*)(W2lf + (size_t)ks * 1536 + n4);
      acc[s] = __builtin_amdgcn_mfma_f32_16x16x32_bf16(a, bh, acc[s], 0, 0, 0);
      acc[s] = __builtin_amdgcn_mfma_f32_16x16x32_bf16(a, bl, acc[s], 0, 0, 0);
    }
  }

  float ps[4];
#pragma unroll
  for (int q = 0; q < 4; ++q)
    ps[q] = acc[0][q] * acc[0][q] + acc[1][q] * acc[1][q] + acc[2][q] * acc[2][q];
#pragma unroll
  for (int m = 1; m < 16; m <<= 1)
#pragma unroll
    for (int q = 0; q < 4; ++q) ps[q] += __shfl_xor(ps[q], m);

#pragma unroll
  for (int q = 0; q < 4; ++q) {
    const int gr = wr0 + (g << 2) + q;
    if (gr < N_NODES) {
      float rn = 1.f / fmaxf(sqrtf(ps[q]), 1e-12f);
#pragma unroll
      for (int s = 0; s < 3; ++s)
        H0[(size_t)gr * HSTR + s * 16 + fr] = f2bf(acc[s][q] * rn);
      H0[(size_t)gr * HSTR + 48 + fr] = 0;
    }
  }
}

// ------- bf16 H0 -> fp8 row with embedded dinv ---------------------------
// Row (16 uints): slots 0-9 = cols 0-39 fp8; slot 10 = (col40, 0,0,0);
// slot 11 = 0; slot 12 = fp32 dinv bits; slots 13-15 = 0.
__global__ __launch_bounds__(256) void cvt8_kernel(const unsigned* __restrict__ h0b,
                                                   const float* __restrict__ dinv,
                                                   unsigned* __restrict__ h0f) {
  int idx = blockIdx.x * 256 + threadIdx.x;
  if (idx >= N_NODES * 16) return;
  int n = idx >> 4, j = idx & 15;
  unsigned out = 0;
  if (j < 10) {
    unsigned a = h0b[(size_t)n * 32 + 2 * j];
    unsigned b = h0b[(size_t)n * 32 + 2 * j + 1];
    int pk = __builtin_amdgcn_cvt_pk_fp8_f32(bflo(a), bfhi(a), 0, false);
    pk = __builtin_amdgcn_cvt_pk_fp8_f32(bflo(b), bfhi(b), pk, true);
    out = (unsigned)pk;
  } else if (j == 10) {
    unsigned a = h0b[(size_t)n * 32 + 20];
    out = (unsigned)__builtin_amdgcn_cvt_pk_fp8_f32(bflo(a), 0.f, 0, false);
  } else if (j == 12) {
    out = __float_as_uint(dinv[n]);
  }
  h0f[idx] = out;
}

// ---------------- exclusive scan over node degrees (3 kernels) -----------
__global__ __launch_bounds__(256) void scan1_kernel(const unsigned* __restrict__ deg,
                                                    unsigned* __restrict__ offs,
                                                    unsigned* __restrict__ btot) {
  __shared__ unsigned wsum[4];
  __shared__ unsigned wbase[4];
  const int t = threadIdx.x, lane = t & 63, w = t >> 6;
  const int base = blockIdx.x * 1024 + t * 4;
  unsigned v[4];
#pragma unroll
  for (int i = 0; i < 4; ++i) {
    int idx = base + i;
    v[i] = (idx < N_NODES) ? deg[idx] : 0u;
  }
  unsigned tsum = v[0] + v[1] + v[2] + v[3];
  unsigned inc = tsum;
  for (int d = 1; d < 64; d <<= 1) {
    unsigned n = (unsigned)__shfl_up((int)inc, d);
    if (lane >= d) inc += n;
  }
  if (lane == 63) wsum[w] = inc;
  __syncthreads();
  if (t == 0) {
    unsigned run = 0;
    for (int i = 0; i < 4; ++i) { unsigned s = wsum[i]; wbase[i] = run; run += s; }
    btot[blockIdx.x] = run;
  }
  __syncthreads();
  unsigned ex = wbase[w] + inc - tsum;
#pragma unroll
  for (int i = 0; i < 4; ++i) {
    int idx = base + i;
    if (idx < N_NODES) offs[idx] = ex;
    ex += v[i];
  }
}

__global__ __launch_bounds__(128) void scan2_kernel(const unsigned* __restrict__ btot,
                                                    unsigned* __restrict__ bbase, int B) {
  __shared__ unsigned wsum[2];
  __shared__ unsigned wbase[2];
  const int t = threadIdx.x, lane = t & 63, w = t >> 6;
  unsigned v = (t < B) ? btot[t] : 0u;
  unsigned inc = v;
  for (int d = 1; d < 64; d <<= 1) {
    unsigned n = (unsigned)__shfl_up((int)inc, d);
    if (lane >= d) inc += n;
  }
  if (lane == 63) wsum[w] = inc;
  __syncthreads();
  if (t == 0) {
    unsigned run = 0;
    for (int i = 0; i < 2; ++i) { unsigned s = wsum[i]; wbase[i] = run; run += s; }
  }
  __syncthreads();
  unsigned ex = wbase[w] + inc - v;
  if (t < B) bbase[t] = ex;
}

__global__ __launch_bounds__(256) void scan3_kernel(unsigned* __restrict__ offs,
                                                    const unsigned* __restrict__ bbase) {
  int i = blockIdx.x * 256 + threadIdx.x;
  if (i < N_NODES) offs[i] += bbase[i >> 10];
}

// ----- APPNP iteration: fp8 rows w/ embedded dinv, 4 nodes/wave ----------
__global__ __launch_bounds__(256) void prop_kernel(
    const unsigned* __restrict__ hsrc,   // fp8 rows, 16 uints/row
    const unsigned* __restrict__ h0b,    // bf16 H0, 32 uints/row
    unsigned* __restrict__ hdst,         // fp8 rows (when fout == nullptr)
    float* __restrict__ fout,            // non-null on last iteration
    const unsigned* __restrict__ rec4,   // CSC: source node per edge
    const unsigned* __restrict__ offs,
    const unsigned* __restrict__ deg) {
  const int wv = threadIdx.x >> 6;
  const int lane = threadIdx.x & 63;
  const int sub = lane & 15;           // uint index within 64-B row
  const int n = blockIdx.x * 16 + wv * 4 + (lane >> 4);
  if (n >= N_NODES) return;
  const int sf = (lane & 48) + 12;     // shfl source lane holding dinv bits
  const unsigned s = offs[n];
  const unsigned e = s + deg[n];
  float a0 = 0.f, a1 = 0.f, a2 = 0.f, a3 = 0.f;
  float c0 = 0.f, c1 = 0.f, c2 = 0.f, c3 = 0.f;

#define ACC8(U, W, A0, A1, A2, A3)                                        \
  { f32x2 lo = __builtin_amdgcn_cvt_pk_f32_fp8((int)(U), false);          \
    f32x2 hi = __builtin_amdgcn_cvt_pk_f32_fp8((int)(U), true);           \
    A0 += lo.x * (W); A1 += lo.y * (W);                                   \
    A2 += hi.x * (W); A3 += hi.y * (W); }

  // self row (also provides dinv_n via shfl from slot 12)
  unsigned su = hsrc[(size_t)n * 16 + sub];
  float dn = __uint_as_float(__shfl((int)su, sf));

  unsigned i = s;
  for (; i + 8 <= e; i += 8) {
    unsigned r0 = rec4[i],     r1 = rec4[i + 1], r2 = rec4[i + 2], r3 = rec4[i + 3];
    unsigned r4 = rec4[i + 4], r5 = rec4[i + 5], r6 = rec4[i + 6], r7 = rec4[i + 7];
    unsigned u0 = hsrc[(size_t)r0 * 16 + sub];
    unsigned u1 = hsrc[(size_t)r1 * 16 + sub];
    unsigned u2 = hsrc[(size_t)r2 * 16 + sub];
    unsigned u3 = hsrc[(size_t)r3 * 16 + sub];
    unsigned u4 = hsrc[(size_t)r4 * 16 + sub];
    unsigned u5 = hsrc[(size_t)r5 * 16 + sub];
    unsigned u6 = hsrc[(size_t)r6 * 16 + sub];
    unsigned u7 = hsrc[(size_t)r7 * 16 + sub];
    float d0 = __uint_as_float(__shfl((int)u0, sf));
    float d1 = __uint_as_float(__shfl((int)u1, sf));
    float d2 = __uint_as_float(__shfl((int)u2, sf));
    float d3 = __uint_as_float(__shfl((int)u3, sf));
    float d4 = __uint_as_float(__shfl((int)u4, sf));
    float d5 = __uint_as_float(__shfl((int)u5, sf));
    float d6 = __uint_as_float(__shfl((int)u6, sf));
    float d7 = __uint_as_float(__shfl((int)u7, sf));
    ACC8(u0, d0, a0, a1, a2, a3);
    ACC8(u1, d1, c0, c1, c2, c3);
    ACC8(u2, d2, a0, a1, a2, a3);
    ACC8(u3, d3, c0, c1, c2, c3);
    ACC8(u4, d4, a0, a1, a2, a3);
    ACC8(u5, d5, c0, c1, c2, c3);
    ACC8(u6, d6, a0, a1, a2, a3);
    ACC8(u7, d7, c0, c1, c2, c3);
  }
  for (; i < e; ++i) {
    unsigned r = rec4[i];
    unsigned u = hsrc[(size_t)r * 16 + sub];
    float d = __uint_as_float(__shfl((int)u, sf));
    ACC8(u, d, a0, a1, a2, a3);
  }
  // self-loop: weight dinv_n (then whole sum scaled by dinv_n)
  ACC8(su, dn, a0, a1, a2, a3);

  unsigned hu0 = h0b[(size_t)n * 32 + 2 * sub];
  unsigned hu1 = h0b[(size_t)n * 32 + 2 * sub + 1];
  const float sc9 = 0.9f * dn;
  float o0 = sc9 * (a0 + c0) + 0.1f * bflo(hu0);
  float o1 = sc9 * (a1 + c1) + 0.1f * bfhi(hu0);
  float o2 = sc9 * (a2 + c2) + 0.1f * bflo(hu1);
  float o3 = sc9 * (a3 + c3) + 0.1f * bfhi(hu1);
  if (fout) {
    int c = 4 * sub;
    if (c < OUTC)     fout[(size_t)n * OUTC + c] = o0;
    if (c + 1 < OUTC) fout[(size_t)n * OUTC + c + 1] = o1;
    if (c + 2 < OUTC) fout[(size_t)n * OUTC + c + 2] = o2;
    if (c + 3 < OUTC) fout[(size_t)n * OUTC + c + 3] = o3;
  } else {
    unsigned outw = 0;
    if (sub < 10) {
      int pk = __builtin_amdgcn_cvt_pk_fp8_f32(o0, o1, 0, false);
      pk = __builtin_amdgcn_cvt_pk_fp8_f32(o2, o3, pk, true);
      outw = (unsigned)pk;
    } else if (sub == 10) {
      outw = (unsigned)__builtin_amdgcn_cvt_pk_fp8_f32(o0, 0.f, 0, false);
    } else if (sub == 12) {
      outw = __float_as_uint(dn);
    }
    hdst[(size_t)n * 16 + sub] = outw;
  }
}

// ---------------- host ----------------
extern "C" void kernel_launch(void* const* d_in, const int* in_sizes, int n_in,
                              void* d_out, int out_size, void* d_ws, size_t ws_size,
                              hipStream_t stream) {
  const float* x  = (const float*)d_in[0];
  const int*   ei = (const int*)d_in[1];
  const float* W1 = (const float*)d_in[2];
  const float* b1 = (const float*)d_in[3];
  const float* W2 = (const float*)d_in[4];
  const float* b2 = (const float*)d_in[5];
  float* out = (float*)d_out;

  char* p = (char*)d_ws;
  auto alloc = [&](size_t bytes) {
    char* q = p;
    p += (bytes + 255) & ~(size_t)255;
    return q;
  };
  unsigned* deg    = (unsigned*)alloc((size_t)N_NODES * 4);
  float*    dinv   = (float*)   alloc((size_t)N_NODES * 4);
  unsigned* offs   = (unsigned*)alloc((size_t)N_NODES * 4);
  unsigned* btot   = (unsigned*)alloc(128 * 4);
  unsigned* bbase  = (unsigned*)alloc(128 * 4);
  unsigned* cursor = (unsigned*)alloc((size_t)N_NODES * 4);
  unsigned* bhist  = (unsigned*)alloc((NBUK + 1) * 4);
  unsigned* bbase2 = (unsigned*)alloc((NBUK + 1) * 4);
  unsigned* gcur   = (unsigned*)alloc((NBUK + 1) * 4);
  unsigned* binned = (unsigned*)alloc((size_t)N_EDGES * 4);
  unsigned* rec4   = (unsigned*)alloc((size_t)N_EDGES * 4);
  unsigned short* H0b = (unsigned short*)alloc((size_t)N_NODES * HSTR * 2);
  unsigned* H0f = (unsigned*)alloc((size_t)N_NODES * 16 * 4);
  unsigned* HA  = (unsigned*)alloc((size_t)N_NODES * 16 * 4);
  unsigned* HB  = (unsigned*)alloc((size_t)N_NODES * 16 * 4);
  unsigned short* h1g = (unsigned short*)alloc((size_t)N_NODES * HID_C * 2);
  unsigned short* Whf = (unsigned short*)alloc((size_t)NT * 8192 * 2);
  unsigned short* W2hf = (unsigned short*)alloc((size_t)8 * 1536 * 2);
  unsigned short* W2lf = (unsigned short*)alloc((size_t)8 * 1536 * 2);

  const int* row = ei;            // edge_index[0] : sources
  const int* col = ei + N_EDGES;  // edge_index[1] : targets

  hipMemsetAsync(deg, 0, (size_t)N_NODES * 4, stream);
  hipMemsetAsync(cursor, 0, (size_t)N_NODES * 4, stream);
  hipMemsetAsync(bhist, 0, (NBUK + 1) * 4, stream);
  hipMemsetAsync(gcur, 0, (NBUK + 1) * 4, stream);

  deg_kernel<<<(N_EDGES + 255) / 256, 256, 0, stream>>>(col, deg);
  bhist_kernel<<<256, 256, 0, stream>>>(col, bhist);
  dinv_kernel<<<(N_NODES + 255) / 256, 256, 0, stream>>>(deg, dinv);
  wprep1_kernel<<<(HID_C * KPAD + 255) / 256, 256, 0, stream>>>(W1, Whf);
  wprep2_kernel<<<(48 * HID_C + 255) / 256, 256, 0, stream>>>(W2, W2hf, W2lf);
  gemm1_kernel<<<(N_NODES + 63) / 64, 256, 0, stream>>>(x, Whf, b1, h1g);
  gemm2_kernel<<<(N_NODES + 63) / 64, 256, 0, stream>>>(h1g, W2hf, W2lf, b2, H0b);
  cvt8_kernel<<<(N_NODES * 16 + 255) / 256, 256, 0, stream>>>((const unsigned*)H0b, dinv, H0f);

  const int B = (N_NODES + 1023) / 1024;  // 98
  scan1_kernel<<<B, 256, 0, stream>>>(deg, offs, btot);
  scan2_kernel<<<1, 128, 0, stream>>>(btot, bbase, B);
  scan3_kernel<<<(N_NODES + 255) / 256, 256, 0, stream>>>(offs, bbase);
  scanb_kernel<<<1, 512, 0, stream>>>(bhist, bbase2);
  bin_kernel<<<(N_EDGES + 255) / 256, 256, 0, stream>>>(row, col, bbase2, gcur, binned);
  place_kernel<<<NBUK, 256, 0, stream>>>(binned, bbase2, bhist, offs, cursor, rec4);

  const unsigned* src = H0f;
  unsigned* bufs[2] = {HA, HB};
  for (int k = 0; k < K_ITERS; ++k) {
    bool last = (k == K_ITERS - 1);
    unsigned* dst = last ? nullptr : bufs[k & 1];
    float* fdst = last ? out : nullptr;
    prop_kernel<<<(N_NODES + 15) / 16, 256, 0, stream>>>(
        src, (const unsigned*)H0b, dst, fdst, rec4, offs, deg);
    src = dst;
  }
}

// Round 10
// 894.860 us; speedup vs baseline: 2.1589x; 2.1589x over previous
//
#include <hip/hip_runtime.h>

#define N_NODES 100000
#define N_EDGES 3200000
#define IN_C 602
#define KPAD 608
#define NT 19           // KPAD/32 k-tiles
#define HID_C 256
#define OUTC 41
#define HSTR 64         // bf16 h0 row stride (128 B)
#define K_ITERS 10
#define NBUK 391        // ceil(N_NODES/256) buckets for binned CSC build
#define NBLK_BIN 256    // blocks in binA/binB
#define CHUNK 12500     // edges per bin block (256*12500 = 3.2M)

typedef __attribute__((ext_vector_type(8))) short bf16x8;
typedef __attribute__((ext_vector_type(4))) float f32x4;
typedef __attribute__((ext_vector_type(2))) float f32x2;

static __device__ __forceinline__ unsigned short f2bf(float f) {
  unsigned u = __float_as_uint(f);
  u += 0x7fffu + ((u >> 16) & 1u);
  return (unsigned short)(u >> 16);
}
static __device__ __forceinline__ float bf2f(unsigned short h) {
  return __uint_as_float(((unsigned)h) << 16);
}
static __device__ __forceinline__ float bflo(unsigned u) {
  return __uint_as_float(u << 16);
}
static __device__ __forceinline__ float bfhi(unsigned u) {
  return __uint_as_float(u & 0xffff0000u);
}

// ---------------- degree ----------------
__global__ __launch_bounds__(256) void deg_kernel(const int* __restrict__ col,
                                                  unsigned* __restrict__ deg) {
  int e = blockIdx.x * 256 + threadIdx.x;
  if (e < N_EDGES) atomicAdd(&deg[col[e]], 1u);
}

__global__ __launch_bounds__(256) void dinv_kernel(const unsigned* __restrict__ deg,
                                                   float* __restrict__ dinv) {
  int i = blockIdx.x * 256 + threadIdx.x;
  if (i < N_NODES) dinv[i] = rsqrtf((float)(deg[i] + 1u));
}

// ------- binA: per-block bucket histograms (LDS-aggregated, no contention)
__global__ __launch_bounds__(256) void binA_kernel(const int* __restrict__ col,
                                                   unsigned* __restrict__ gh) {
  __shared__ unsigned lh[NBUK];
  const int tid = threadIdx.x, blk = blockIdx.x;
  for (int i = tid; i < NBUK; i += 256) lh[i] = 0;
  __syncthreads();
  const int start = blk * CHUNK;
  const int end = (start + CHUNK < N_EDGES) ? start + CHUNK : N_EDGES;
  for (int e = start + tid; e < end; e += 256)
    atomicAdd(&lh[col[e] >> 8], 1u);
  __syncthreads();
  for (int i = tid; i < NBUK; i += 256)
    gh[(size_t)i * NBLK_BIN + blk] = lh[i];
}

// ------- binScan: bucket totals -> bbase2; gh -> per-(bucket,block) bases
__global__ __launch_bounds__(512) void binScan_kernel(unsigned* __restrict__ gh,
                                                      unsigned* __restrict__ bbase2,
                                                      unsigned* __restrict__ bhist) {
  __shared__ unsigned wsum[8];
  __shared__ unsigned wbase[8];
  const int t = threadIdx.x, lane = t & 63, w = t >> 6;
  unsigned tot = 0;
  if (t < NBUK) {
    unsigned* gp = gh + (size_t)t * NBLK_BIN;
#pragma unroll 8
    for (int j = 0; j < NBLK_BIN; ++j) tot += gp[j];
  }
  unsigned inc = tot;
  for (int d = 1; d < 64; d <<= 1) {
    unsigned x = (unsigned)__shfl_up((int)inc, d);
    if (lane >= d) inc += x;
  }
  if (lane == 63) wsum[w] = inc;
  __syncthreads();
  if (t == 0) {
    unsigned run = 0;
    for (int i = 0; i < 8; ++i) { unsigned s = wsum[i]; wbase[i] = run; run += s; }
  }
  __syncthreads();
  if (t < NBUK) {
    unsigned base = wbase[w] + inc - tot;
    bbase2[t] = base;
    bhist[t] = tot;
    unsigned* gp = gh + (size_t)t * NBLK_BIN;
    unsigned run = base;
#pragma unroll 8
    for (int j = 0; j < NBLK_BIN; ++j) {
      unsigned v = gp[j];
      gp[j] = run;
      run += v;
    }
  }
}

// ------- binB: COO -> bucket-grouped packed records (reserved runs) -------
// record = (c & 255) << 17 | r   (r < 2^17, 4 bytes)
__global__ __launch_bounds__(256) void binB_kernel(const int* __restrict__ row,
                                                   const int* __restrict__ col,
                                                   const unsigned* __restrict__ gh,
                                                   unsigned* __restrict__ binned) {
  __shared__ unsigned lbase[NBUK];
  __shared__ unsigned lcur[NBUK];
  const int tid = threadIdx.x, blk = blockIdx.x;
  for (int i = tid; i < NBUK; i += 256) {
    lbase[i] = gh[(size_t)i * NBLK_BIN + blk];
    lcur[i] = 0;
  }
  __syncthreads();
  const int start = blk * CHUNK;
  const int end = (start + CHUNK < N_EDGES) ? start + CHUNK : N_EDGES;
  for (int e = start + tid; e < end; e += 256) {
    int r = row[e], c = col[e];
    int b = c >> 8;
    unsigned idx = atomicAdd(&lcur[b], 1u);
    binned[lbase[b] + idx] = (((unsigned)(c & 255)) << 17) | (unsigned)r;
  }
}

// ---------------- place pass: bucket-grouped -> exact CSC (rec4 = r) ------
__global__ __launch_bounds__(256) void place_kernel(const unsigned* __restrict__ binned,
                                                    const unsigned* __restrict__ bbase2,
                                                    const unsigned* __restrict__ bhist,
                                                    const unsigned* __restrict__ offs,
                                                    unsigned* __restrict__ cursor,
                                                    unsigned* __restrict__ rec4) {
  const int b = blockIdx.x;
  const unsigned s = bbase2[b];
  const unsigned cnt = bhist[b];
  for (unsigned i = threadIdx.x; i < cnt; i += 256) {
    unsigned v = binned[s + i];
    int c = (b << 8) | (int)(v >> 17);
    unsigned r = v & 0x1FFFFu;
    unsigned pos = offs[c] + atomicAdd(&cursor[c], 1u);
    rec4[pos] = r;
  }
}

// ------- W1 bf16 (nearest) in fragment-linear layout [t][n][g][8] --------
__global__ __launch_bounds__(256) void wprep1_kernel(const float* __restrict__ W1,
                                                     unsigned short* __restrict__ Whf) {
  int idx = blockIdx.x * 256 + threadIdx.x;
  if (idx >= HID_C * KPAD) return;
  int n = idx / KPAD, k = idx % KPAD;
  float v = (k < IN_C) ? W1[n * IN_C + k] : 0.f;
  int t = k >> 5, g = (k >> 3) & 3, j = k & 7;
  Whf[(size_t)t * 8192 + (((n << 2) + g) << 3) + j] = f2bf(v);
}

// ------- W2 hi/lo split, fragment-linear [ks][n(48)][g][8] ---------------
__global__ __launch_bounds__(256) void wprep2_kernel(const float* __restrict__ W2,
                                                     unsigned short* __restrict__ W2hf,
                                                     unsigned short* __restrict__ W2lf) {
  int idx = blockIdx.x * 256 + threadIdx.x;
  if (idx >= 48 * HID_C) return;
  int n = idx >> 8, k = idx & 255;
  float v = (n < OUTC) ? W2[n * HID_C + k] : 0.f;
  unsigned short hi = f2bf(v);
  int ks = k >> 5, g = (k >> 3) & 3, j = k & 7;
  size_t dst = (size_t)ks * 1536 + (((n << 2) + g) << 3) + j;
  W2hf[dst] = hi;
  W2lf[dst] = f2bf(v - bf2f(hi));
}

// ---------------- GEMM1: h1 = relu(x @ W1^T + b1), bf16 out --------------
__global__ __launch_bounds__(256, 3) void gemm1_kernel(
    const float* __restrict__ x,
    const unsigned short* __restrict__ Whf,
    const float* __restrict__ b1,
    unsigned short* __restrict__ h1g) {
  __shared__ __align__(16) float4 xt[3 * 512];        // 24 KB; reused as h1t
  unsigned short* h1t = (unsigned short*)xt;          // [32][264] in epilogue

  const int tid = threadIdx.x;
  const int lane = tid & 63;
  const int w = tid >> 6;
  const int r0 = blockIdx.x * 64;
  const int fr = lane & 15;
  const int g = lane >> 4;

  const int srow = tid >> 3;
  const int sc = tid & 7;
  int gr0 = r0 + srow;       if (gr0 >= N_NODES) gr0 = N_NODES - 1;
  int gr1 = r0 + srow + 32;  if (gr1 >= N_NODES) gr1 = N_NODES - 1;
  const float* xp0 = x + (size_t)gr0 * IN_C;
  const float* xp1 = x + (size_t)gr1 * IN_C;
  const int ws0 = srow * 8 + (sc ^ (srow & 7));
  const int ws1 = (srow + 32) * 8 + (sc ^ (srow & 7));

  f32x4 acc[4][4];
  {
    const int bcol0 = (w << 6) + fr;
#pragma unroll
    for (int s = 0; s < 4; ++s) {
      float bv = b1[bcol0 + s * 16];
#pragma unroll
      for (int mi = 0; mi < 4; ++mi) acc[mi][s] = (f32x4){bv, bv, bv, bv};
    }
  }

  float4 pA0, pA1, pB0, pB1;
  bf16x8 bhv[2][4];

#define STAGE_LOAD0(T)                                                     \
  { const int kb = (T) * 32 + sc * 4;                                      \
    if ((T) < NT - 1) { pA0 = *(const float4*)(xp0 + kb);                  \
                        pA1 = *(const float4*)(xp1 + kb); }                \
    else { float t0[4], t1[4];                                             \
      _Pragma("unroll") for (int j = 0; j < 4; ++j) { int k = kb + j;      \
        t0[j] = (k < IN_C) ? xp0[k] : 0.f; t1[j] = (k < IN_C) ? xp1[k] : 0.f; } \
      pA0 = (float4){t0[0], t0[1], t0[2], t0[3]};                          \
      pA1 = (float4){t1[0], t1[1], t1[2], t1[3]}; } }

#define STAGE_LOAD1(T)                                                     \
  { const int kb = (T) * 32 + sc * 4;                                      \
    if ((T) < NT - 1) { pB0 = *(const float4*)(xp0 + kb);                  \
                        pB1 = *(const float4*)(xp1 + kb); }                \
    else { float t0[4], t1[4];                                             \
      _Pragma("unroll") for (int j = 0; j < 4; ++j) { int k = kb + j;      \
        t0[j] = (k < IN_C) ? xp0[k] : 0.f; t1[j] = (k < IN_C) ? xp1[k] : 0.f; } \
      pB0 = (float4){t0[0], t0[1], t0[2], t0[3]};                          \
      pB1 = (float4){t1[0], t1[1], t1[2], t1[3]}; } }

#define STAGE_WRITE0(BW) { xt[(BW) * 512 + ws0] = pA0; xt[(BW) * 512 + ws1] = pA1; }
#define STAGE_WRITE1(BW) { xt[(BW) * 512 + ws0] = pB0; xt[(BW) * 512 + ws1] = pB1; }

#define LOADB(T, PAR)                                                      \
  { const size_t tb = (size_t)(T) * 8192;                                  \
    _Pragma("unroll") for (int s = 0; s < 4; ++s) {                        \
      const int n4 = (((w << 6) + s * 16 + fr) << 2) + g;                  \
      bhv[PAR][s] = *(const bf16x8*)(Whf + tb + n4 * 8);                   \
    } }

#define COMPUTE(BR, PAR)                                                   \
  { _Pragma("unroll") for (int mi = 0; mi < 4; ++mi) {                     \
      const int rr = mi * 16 + fr;                                         \
      float4 pa = xt[(BR) * 512 + rr * 8 + ((2 * g) ^ (fr & 7))];          \
      float4 pb = xt[(BR) * 512 + rr * 8 + ((2 * g + 1) ^ (fr & 7))];      \
      union { unsigned u[4]; bf16x8 v; } hh, ll;                           \
      asm("v_cvt_pk_bf16_f32 %0, %1, %2" : "=v"(hh.u[0]) : "v"(pa.x), "v"(pa.y)); \
      asm("v_cvt_pk_bf16_f32 %0, %1, %2" : "=v"(hh.u[1]) : "v"(pa.z), "v"(pa.w)); \
      asm("v_cvt_pk_bf16_f32 %0, %1, %2" : "=v"(hh.u[2]) : "v"(pb.x), "v"(pb.y)); \
      asm("v_cvt_pk_bf16_f32 %0, %1, %2" : "=v"(hh.u[3]) : "v"(pb.z), "v"(pb.w)); \
      float l0 = pa.x - bflo(hh.u[0]), l1 = pa.y - bfhi(hh.u[0]);          \
      float l2 = pa.z - bflo(hh.u[1]), l3 = pa.w - bfhi(hh.u[1]);          \
      float l4 = pb.x - bflo(hh.u[2]), l5 = pb.y - bfhi(hh.u[2]);          \
      float l6 = pb.z - bflo(hh.u[3]), l7 = pb.w - bfhi(hh.u[3]);          \
      asm("v_cvt_pk_bf16_f32 %0, %1, %2" : "=v"(ll.u[0]) : "v"(l0), "v"(l1)); \
      asm("v_cvt_pk_bf16_f32 %0, %1, %2" : "=v"(ll.u[1]) : "v"(l2), "v"(l3)); \
      asm("v_cvt_pk_bf16_f32 %0, %1, %2" : "=v"(ll.u[2]) : "v"(l4), "v"(l5)); \
      asm("v_cvt_pk_bf16_f32 %0, %1, %2" : "=v"(ll.u[3]) : "v"(l6), "v"(l7)); \
      _Pragma("unroll") for (int s = 0; s < 4; ++s) {                      \
        acc[mi][s] = __builtin_amdgcn_mfma_f32_16x16x32_bf16(              \
            hh.v, bhv[PAR][s], acc[mi][s], 0, 0, 0);                       \
        acc[mi][s] = __builtin_amdgcn_mfma_f32_16x16x32_bf16(              \
            ll.v, bhv[PAR][s], acc[mi][s], 0, 0, 0);                       \
      } } }

#define BODY(T, PAR)                                                       \
  { int bW = bR + 1; if (bW == 3) bW = 0;                                  \
    if ((T) + 1 < NT) {                                                    \
      if ((PAR) == 0) STAGE_WRITE1(bW) else STAGE_WRITE0(bW);              \
      if ((T) + 3 < NT) { if ((PAR) == 0) STAGE_LOAD1((T) + 3)             \
                          else STAGE_LOAD0((T) + 3); }                     \
      LOADB((T) + 1, (PAR) ^ 1);                                           \
    }                                                                      \
    COMPUTE(bR, PAR);                                                      \
    __syncthreads();                                                       \
    bR = bW; }

  STAGE_LOAD0(0);
  STAGE_WRITE0(0);
  STAGE_LOAD1(1);
  STAGE_LOAD0(2);
  LOADB(0, 0);
  __syncthreads();

  int bR = 0;
  for (int t = 0; t + 1 < NT; t += 2) {
    BODY(t, 0);
    BODY(t + 1, 1);
  }
  BODY(NT - 1, 0);  // NT odd: tail tile, parity 0

  // epilogue: coalesced h1 store via 2 LDS chunks of 32 rows
#pragma unroll
  for (int ch = 0; ch < 2; ++ch) {
#pragma unroll
    for (int mi2 = 0; mi2 < 2; ++mi2) {
      const int mi = ch * 2 + mi2;
#pragma unroll
      for (int s = 0; s < 4; ++s)
#pragma unroll
        for (int q = 0; q < 4; ++q) {
          int rr = mi2 * 16 + (g << 2) + q;
          int cc = (w << 6) + s * 16 + fr;
          h1t[rr * 264 + cc] = f2bf(fmaxf(acc[mi][s][q], 0.f));
        }
    }
    __syncthreads();
    {
      const int row = tid >> 3, seg = tid & 7;
      const int gr = r0 + ch * 32 + row;
      if (gr < N_NODES) {
        const uint4* src = (const uint4*)&h1t[row * 264 + seg * 32];
        uint4* dst = (uint4*)(h1g + (size_t)gr * 256 + seg * 32);
        dst[0] = src[0];
        dst[1] = src[1];
        dst[2] = src[2];
        dst[3] = src[3];
      }
    }
    __syncthreads();
  }
}

// ------- GEMM2 + L2 norm: H0 = normalize(h1 @ W2^T + b2), bf16 out -------
__global__ __launch_bounds__(256) void gemm2_kernel(
    const unsigned short* __restrict__ h1g,
    const unsigned short* __restrict__ W2hf,
    const unsigned short* __restrict__ W2lf,
    const float* __restrict__ b2,
    unsigned short* __restrict__ H0) {
  const int tid = threadIdx.x;
  const int lane = tid & 63;
  const int w = tid >> 6;
  const int fr = lane & 15;
  const int g = lane >> 4;
  const int wr0 = blockIdx.x * 64 + w * 16;

  f32x4 acc[3];
#pragma unroll
  for (int s = 0; s < 3; ++s) {
    int c = s * 16 + fr;
    float bv = (c < OUTC) ? b2[c] : 0.f;
    acc[s] = (f32x4){bv, bv, bv, bv};
  }

  int ar = wr0 + fr;
  if (ar >= N_NODES) ar = N_NODES - 1;
  const unsigned short* ap = h1g + (size_t)ar * 256 + g * 8;

#pragma unroll
  for (int ks = 0; ks < 8; ++ks) {
    bf16x8 a = *(const bf16x8*)(ap + ks * 32);
#pragma unroll
    for (int s = 0; s < 3; ++s) {
      const int n4 = (((s * 16 + fr) << 2) + g) << 3;
      bf16x8 bh = *(const bf16x8*)(W2hf + (size_t)ks * 1536 + n4);
      bf16x8 bl = *(const bf16x8*)(W2lf + (size_t)ks * 1536 + n4);
      acc[s] = __builtin_amdgcn_mfma_f32_16x16x32_bf16(a, bh, acc[s], 0, 0, 0);
      acc[s] = __builtin_amdgcn_mfma_f32_16x16x32_bf16(a, bl, acc[s], 0, 0, 0);
    }
  }

  float ps[4];
#pragma unroll
  for (int q = 0; q < 4; ++q)
    ps[q] = acc[0][q] * acc[0][q] + acc[1][q] * acc[1][q] + acc[2][q] * acc[2][q];
#pragma unroll
  for (int m = 1; m < 16; m <<= 1)
#pragma unroll
    for (int q = 0; q < 4; ++q) ps[q] += __shfl_xor(ps[q], m);

#pragma unroll
  for (int q = 0; q < 4; ++q) {
    const int gr = wr0 + (g << 2) + q;
    if (gr < N_NODES) {
      float rn = 1.f / fmaxf(sqrtf(ps[q]), 1e-12f);
#pragma unroll
      for (int s = 0; s < 3; ++s)
        H0[(size_t)gr * HSTR + s * 16 + fr] = f2bf(acc[s][q] * rn);
      H0[(size_t)gr * HSTR + 48 + fr] = 0;
    }
  }
}

// ------- bf16 H0 -> fp8 row with embedded dinv ---------------------------
// Row (16 uints): slots 0-9 = cols 0-39 fp8; slot 10 = (col40, 0,0,0);
// slot 11 = 0; slot 12 = fp32 dinv bits; slots 13-15 = 0.
__global__ __launch_bounds__(256) void cvt8_kernel(const unsigned* __restrict__ h0b,
                                                   const float* __restrict__ dinv,
                                                   unsigned* __restrict__ h0f) {
  int idx = blockIdx.x * 256 + threadIdx.x;
  if (idx >= N_NODES * 16) return;
  int n = idx >> 4, j = idx & 15;
  unsigned out = 0;
  if (j < 10) {
    unsigned a = h0b[(size_t)n * 32 + 2 * j];
    unsigned b = h0b[(size_t)n * 32 + 2 * j + 1];
    int pk = __builtin_amdgcn_cvt_pk_fp8_f32(bflo(a), bfhi(a), 0, false);
    pk = __builtin_amdgcn_cvt_pk_fp8_f32(bflo(b), bfhi(b), pk, true);
    out = (unsigned)pk;
  } else if (j == 10) {
    unsigned a = h0b[(size_t)n * 32 + 20];
    out = (unsigned)__builtin_amdgcn_cvt_pk_fp8_f32(bflo(a), 0.f, 0, false);
  } else if (j == 12) {
    out = __float_as_uint(dinv[n]);
  }
  h0f[idx] = out;
}

// ---------------- exclusive scan over node degrees (3 kernels) -----------
__global__ __launch_bounds__(256) void scan1_kernel(const unsigned* __restrict__ deg,
                                                    unsigned* __restrict__ offs,
                                                    unsigned* __restrict__ btot) {
  __shared__ unsigned wsum[4];
  __shared__ unsigned wbase[4];
  const int t = threadIdx.x, lane = t & 63, w = t >> 6;
  const int base = blockIdx.x * 1024 + t * 4;
  unsigned v[4];
#pragma unroll
  for (int i = 0; i < 4; ++i) {
    int idx = base + i;
    v[i] = (idx < N_NODES) ? deg[idx] : 0u;
  }
  unsigned tsum = v[0] + v[1] + v[2] + v[3];
  unsigned inc = tsum;
  for (int d = 1; d < 64; d <<= 1) {
    unsigned n = (unsigned)__shfl_up((int)inc, d);
    if (lane >= d) inc += n;
  }
  if (lane == 63) wsum[w] = inc;
  __syncthreads();
  if (t == 0) {
    unsigned run = 0;
    for (int i = 0; i < 4; ++i) { unsigned s = wsum[i]; wbase[i] = run; run += s; }
    btot[blockIdx.x] = run;
  }
  __syncthreads();
  unsigned ex = wbase[w] + inc - tsum;
#pragma unroll
  for (int i = 0; i < 4; ++i) {
    int idx = base + i;
    if (idx < N_NODES) offs[idx] = ex;
    ex += v[i];
  }
}

__global__ __launch_bounds__(128) void scan2_kernel(const unsigned* __restrict__ btot,
                                                    unsigned* __restrict__ bbase, int B) {
  __shared__ unsigned wsum[2];
  __shared__ unsigned wbase[2];
  const int t = threadIdx.x, lane = t & 63, w = t >> 6;
  unsigned v = (t < B) ? btot[t] : 0u;
  unsigned inc = v;
  for (int d = 1; d < 64; d <<= 1) {
    unsigned n = (unsigned)__shfl_up((int)inc, d);
    if (lane >= d) inc += n;
  }
  if (lane == 63) wsum[w] = inc;
  __syncthreads();
  if (t == 0) {
    unsigned run = 0;
    for (int i = 0; i < 2; ++i) { unsigned s = wsum[i]; wbase[i] = run; run += s; }
  }
  __syncthreads();
  unsigned ex = wbase[w] + inc - v;
  if (t < B) bbase[t] = ex;
}

__global__ __launch_bounds__(256) void scan3_kernel(unsigned* __restrict__ offs,
                                                    const unsigned* __restrict__ bbase) {
  int i = blockIdx.x * 256 + threadIdx.x;
  if (i < N_NODES) offs[i] += bbase[i >> 10];
}

// ----- APPNP iteration: fp8 rows w/ embedded dinv, 4 nodes/wave ----------
__global__ __launch_bounds__(256) void prop_kernel(
    const unsigned* __restrict__ hsrc,   // fp8 rows, 16 uints/row
    const unsigned* __restrict__ h0b,    // bf16 H0, 32 uints/row
    unsigned* __restrict__ hdst,         // fp8 rows (when fout == nullptr)
    float* __restrict__ fout,            // non-null on last iteration
    const unsigned* __restrict__ rec4,   // CSC: source node per edge
    const unsigned* __restrict__ offs,
    const unsigned* __restrict__ deg) {
  const int wv = threadIdx.x >> 6;
  const int lane = threadIdx.x & 63;
  const int sub = lane & 15;           // uint index within 64-B row
  const int n = blockIdx.x * 16 + wv * 4 + (lane >> 4);
  if (n >= N_NODES) return;
  const int sf = (lane & 48) + 12;     // shfl source lane holding dinv bits
  const unsigned s = offs[n];
  const unsigned e = s + deg[n];
  float a0 = 0.f, a1 = 0.f, a2 = 0.f, a3 = 0.f;
  float c0 = 0.f, c1 = 0.f, c2 = 0.f, c3 = 0.f;

#define ACC8(U, W, A0, A1, A2, A3)                                        \
  { f32x2 lo = __builtin_amdgcn_cvt_pk_f32_fp8((int)(U), false);          \
    f32x2 hi = __builtin_amdgcn_cvt_pk_f32_fp8((int)(U), true);           \
    A0 += lo.x * (W); A1 += lo.y * (W);                                   \
    A2 += hi.x * (W); A3 += hi.y * (W); }

  // self row (also provides dinv_n via shfl from slot 12)
  unsigned su = hsrc[(size_t)n * 16 + sub];
  float dn = __uint_as_float(__shfl((int)su, sf));

  unsigned i = s;
  for (; i + 8 <= e; i += 8) {
    unsigned r0 = rec4[i],     r1 = rec4[i + 1], r2 = rec4[i + 2], r3 = rec4[i + 3];
    unsigned r4 = rec4[i + 4], r5 = rec4[i + 5], r6 = rec4[i + 6], r7 = rec4[i + 7];
    unsigned u0 = hsrc[(size_t)r0 * 16 + sub];
    unsigned u1 = hsrc[(size_t)r1 * 16 + sub];
    unsigned u2 = hsrc[(size_t)r2 * 16 + sub];
    unsigned u3 = hsrc[(size_t)r3 * 16 + sub];
    unsigned u4 = hsrc[(size_t)r4 * 16 + sub];
    unsigned u5 = hsrc[(size_t)r5 * 16 + sub];
    unsigned u6 = hsrc[(size_t)r6 * 16 + sub];
    unsigned u7 = hsrc[(size_t)r7 * 16 + sub];
    float d0 = __uint_as_float(__shfl((int)u0, sf));
    float d1 = __uint_as_float(__shfl((int)u1, sf));
    float d2 = __uint_as_float(__shfl((int)u2, sf));
    float d3 = __uint_as_float(__shfl((int)u3, sf));
    float d4 = __uint_as_float(__shfl((int)u4, sf));
    float d5 = __uint_as_float(__shfl((int)u5, sf));
    float d6 = __uint_as_float(__shfl((int)u6, sf));
    float d7 = __uint_as_float(__shfl((int)u7, sf));
    ACC8(u0, d0, a0, a1, a2, a3);
    ACC8(u1, d1, c0, c1, c2, c3);
    ACC8(u2, d2, a0, a1, a2, a3);
    ACC8(u3, d3, c0, c1, c2, c3);
    ACC8(u4, d4, a0, a1, a2, a3);
    ACC8(u5, d5, c0, c1, c2, c3);
    ACC8(u6, d6, a0, a1, a2, a3);
    ACC8(u7, d7, c0, c1, c2, c3);
  }
  for (; i < e; ++i) {
    unsigned r = rec4[i];
    unsigned u = hsrc[(size_t)r * 16 + sub];
    float d = __uint_as_float(__shfl((int)u, sf));
    ACC8(u, d, a0, a1, a2, a3);
  }
  // self-loop: weight dinv_n (then whole sum scaled by dinv_n)
  ACC8(su, dn, a0, a1, a2, a3);

  unsigned hu0 = h0b[(size_t)n * 32 + 2 * sub];
  unsigned hu1 = h0b[(size_t)n * 32 + 2 * sub + 1];
  const float sc9 = 0.9f * dn;
  float o0 = sc9 * (a0 + c0) + 0.1f * bflo(hu0);
  float o1 = sc9 * (a1 + c1) + 0.1f * bfhi(hu0);
  float o2 = sc9 * (a2 + c2) + 0.1f * bflo(hu1);
  float o3 = sc9 * (a3 + c3) + 0.1f * bfhi(hu1);
  if (fout) {
    int c = 4 * sub;
    if (c < OUTC)     fout[(size_t)n * OUTC + c] = o0;
    if (c + 1 < OUTC) fout[(size_t)n * OUTC + c + 1] = o1;
    if (c + 2 < OUTC) fout[(size_t)n * OUTC + c + 2] = o2;
    if (c + 3 < OUTC) fout[(size_t)n * OUTC + c + 3] = o3;
  } else {
    unsigned outw = 0;
    if (sub < 10) {
      int pk = __builtin_amdgcn_cvt_pk_fp8_f32(o0, o1, 0, false);
      pk = __builtin_amdgcn_cvt_pk_fp8_f32(o2, o3, pk, true);
      outw = (unsigned)pk;
    } else if (sub == 10) {
      outw = (unsigned)__builtin_amdgcn_cvt_pk_fp8_f32(o0, 0.f, 0, false);
    } else if (sub == 12) {
      outw = __float_as_uint(dn);
    }
    hdst[(size_t)n * 16 + sub] = outw;
  }
}

// ---------------- host ----------------
extern "C" void kernel_launch(void* const* d_in, const int* in_sizes, int n_in,
                              void* d_out, int out_size, void* d_ws, size_t ws_size,
                              hipStream_t stream) {
  const float* x  = (const float*)d_in[0];
  const int*   ei = (const int*)d_in[1];
  const float* W1 = (const float*)d_in[2];
  const float* b1 = (const float*)d_in[3];
  const float* W2 = (const float*)d_in[4];
  const float* b2 = (const float*)d_in[5];
  float* out = (float*)d_out;

  char* p = (char*)d_ws;
  auto alloc = [&](size_t bytes) {
    char* q = p;
    p += (bytes + 255) & ~(size_t)255;
    return q;
  };
  unsigned* deg    = (unsigned*)alloc((size_t)N_NODES * 4);
  float*    dinv   = (float*)   alloc((size_t)N_NODES * 4);
  unsigned* offs   = (unsigned*)alloc((size_t)N_NODES * 4);
  unsigned* btot   = (unsigned*)alloc(128 * 4);
  unsigned* bbase  = (unsigned*)alloc(128 * 4);
  unsigned* cursor = (unsigned*)alloc((size_t)N_NODES * 4);
  unsigned* bhist  = (unsigned*)alloc((NBUK + 1) * 4);
  unsigned* bbase2 = (unsigned*)alloc((NBUK + 1) * 4);
  unsigned* gh     = (unsigned*)alloc((size_t)NBUK * NBLK_BIN * 4);
  unsigned* binned = (unsigned*)alloc((size_t)N_EDGES * 4);
  unsigned* rec4   = (unsigned*)alloc((size_t)N_EDGES * 4);
  unsigned short* H0b = (unsigned short*)alloc((size_t)N_NODES * HSTR * 2);
  unsigned* H0f = (unsigned*)alloc((size_t)N_NODES * 16 * 4);
  unsigned* HA  = (unsigned*)alloc((size_t)N_NODES * 16 * 4);
  unsigned* HB  = (unsigned*)alloc((size_t)N_NODES * 16 * 4);
  unsigned short* h1g = (unsigned short*)alloc((size_t)N_NODES * HID_C * 2);
  unsigned short* Whf = (unsigned short*)alloc((size_t)NT * 8192 * 2);
  unsigned short* W2hf = (unsigned short*)alloc((size_t)8 * 1536 * 2);
  unsigned short* W2lf = (unsigned short*)alloc((size_t)8 * 1536 * 2);

  const int* row = ei;            // edge_index[0] : sources
  const int* col = ei + N_EDGES;  // edge_index[1] : targets

  hipMemsetAsync(deg, 0, (size_t)N_NODES * 4, stream);
  hipMemsetAsync(cursor, 0, (size_t)N_NODES * 4, stream);

  deg_kernel<<<(N_EDGES + 255) / 256, 256, 0, stream>>>(col, deg);
  dinv_kernel<<<(N_NODES + 255) / 256, 256, 0, stream>>>(deg, dinv);
  wprep1_kernel<<<(HID_C * KPAD + 255) / 256, 256, 0, stream>>>(W1, Whf);
  wprep2_kernel<<<(48 * HID_C + 255) / 256, 256, 0, stream>>>(W2, W2hf, W2lf);
  gemm1_kernel<<<(N_NODES + 63) / 64, 256, 0, stream>>>(x, Whf, b1, h1g);
  gemm2_kernel<<<(N_NODES + 63) / 64, 256, 0, stream>>>(h1g, W2hf, W2lf, b2, H0b);
  cvt8_kernel<<<(N_NODES * 16 + 255) / 256, 256, 0, stream>>>((const unsigned*)H0b, dinv, H0f);

  const int B = (N_NODES + 1023) / 1024;  // 98
  scan1_kernel<<<B, 256, 0, stream>>>(deg, offs, btot);
  scan2_kernel<<<1, 128, 0, stream>>>(btot, bbase, B);
  scan3_kernel<<<(N_NODES + 255) / 256, 256, 0, stream>>>(offs, bbase);
  binA_kernel<<<NBLK_BIN, 256, 0, stream>>>(col, gh);
  binScan_kernel<<<1, 512, 0, stream>>>(gh, bbase2, bhist);
  binB_kernel<<<NBLK_BIN, 256, 0, stream>>>(row, col, gh, binned);
  place_kernel<<<NBUK, 256, 0, stream>>>(binned, bbase2, bhist, offs, cursor, rec4);

  const unsigned* src = H0f;
  unsigned* bufs[2] = {HA, HB};
  for (int k = 0; k < K_ITERS; ++k) {
    bool last = (k == K_ITERS - 1);
    unsigned* dst = last ? nullptr : bufs[k & 1];
    float* fdst = last ? out : nullptr;
    prop_kernel<<<(N_NODES + 15) / 16, 256, 0, stream>>>(
        src, (const unsigned*)H0b, dst, fdst, rec4, offs, deg);
    src = dst;
  }
}

// Round 11
// 685.063 us; speedup vs baseline: 2.8201x; 1.3062x over previous
//
#include <hip/hip_runtime.h>

#define N_NODES 100000
#define N_EDGES 3200000
#define IN_C 602
#define KPAD 608
#define NT 19           // KPAD/32 k-tiles
#define HID_C 256
#define OUTC 41
#define HSTR 64         // bf16 h0 row stride (128 B)
#define K_ITERS 10
#define NBUK 391        // ceil(N_NODES/256) buckets for binned CSC build
#define NBLK_BIN 256    // blocks in binA/binB
#define CHUNK 12500     // edges per bin block (256*12500 = 3.2M)

typedef __attribute__((ext_vector_type(8))) short bf16x8;
typedef __attribute__((ext_vector_type(4))) float f32x4;
typedef __attribute__((ext_vector_type(2))) float f32x2;

static __device__ __forceinline__ unsigned short f2bf(float f) {
  unsigned u = __float_as_uint(f);
  u += 0x7fffu + ((u >> 16) & 1u);
  return (unsigned short)(u >> 16);
}
static __device__ __forceinline__ float bf2f(unsigned short h) {
  return __uint_as_float(((unsigned)h) << 16);
}
static __device__ __forceinline__ float bflo(unsigned u) {
  return __uint_as_float(u << 16);
}
static __device__ __forceinline__ float bfhi(unsigned u) {
  return __uint_as_float(u & 0xffff0000u);
}

// ------- dinv from CSR offsets (deg = offs[i+1]-offs[i]) -----------------
__global__ __launch_bounds__(256) void dinv_kernel(const unsigned* __restrict__ offs,
                                                   float* __restrict__ dinv) {
  int i = blockIdx.x * 256 + threadIdx.x;
  if (i < N_NODES) dinv[i] = rsqrtf((float)(offs[i + 1] - offs[i] + 1u));
}

// ------- binA: per-block bucket histograms (LDS-aggregated, no contention)
__global__ __launch_bounds__(256) void binA_kernel(const int* __restrict__ col,
                                                   unsigned* __restrict__ gh) {
  __shared__ unsigned lh[NBUK];
  const int tid = threadIdx.x, blk = blockIdx.x;
  for (int i = tid; i < NBUK; i += 256) lh[i] = 0;
  __syncthreads();
  const int start = blk * CHUNK;
  const int end = (start + CHUNK < N_EDGES) ? start + CHUNK : N_EDGES;
  for (int e = start + tid; e < end; e += 256)
    atomicAdd(&lh[col[e] >> 8], 1u);
  __syncthreads();
  for (int i = tid; i < NBUK; i += 256)
    gh[(size_t)i * NBLK_BIN + blk] = lh[i];
}

// ------- binScan: bucket totals -> bbase2; gh -> per-(bucket,block) bases
__global__ __launch_bounds__(512) void binScan_kernel(unsigned* __restrict__ gh,
                                                      unsigned* __restrict__ bbase2,
                                                      unsigned* __restrict__ bhist) {
  __shared__ unsigned wsum[8];
  __shared__ unsigned wbase[8];
  const int t = threadIdx.x, lane = t & 63, w = t >> 6;
  unsigned tot = 0;
  if (t < NBUK) {
    unsigned* gp = gh + (size_t)t * NBLK_BIN;
#pragma unroll 8
    for (int j = 0; j < NBLK_BIN; ++j) tot += gp[j];
  }
  unsigned inc = tot;
  for (int d = 1; d < 64; d <<= 1) {
    unsigned x = (unsigned)__shfl_up((int)inc, d);
    if (lane >= d) inc += x;
  }
  if (lane == 63) wsum[w] = inc;
  __syncthreads();
  if (t == 0) {
    unsigned run = 0;
    for (int i = 0; i < 8; ++i) { unsigned s = wsum[i]; wbase[i] = run; run += s; }
  }
  __syncthreads();
  if (t < NBUK) {
    unsigned base = wbase[w] + inc - tot;
    bbase2[t] = base;
    bhist[t] = tot;
    unsigned* gp = gh + (size_t)t * NBLK_BIN;
    unsigned run = base;
#pragma unroll 8
    for (int j = 0; j < NBLK_BIN; ++j) {
      unsigned v = gp[j];
      gp[j] = run;
      run += v;
    }
  }
}

// ------- binB: COO -> bucket-grouped packed records (reserved runs) -------
// record = (c & 255) << 17 | r   (r < 2^17, 4 bytes)
__global__ __launch_bounds__(256) void binB_kernel(const int* __restrict__ row,
                                                   const int* __restrict__ col,
                                                   const unsigned* __restrict__ gh,
                                                   unsigned* __restrict__ binned) {
  __shared__ unsigned lbase[NBUK];
  __shared__ unsigned lcur[NBUK];
  const int tid = threadIdx.x, blk = blockIdx.x;
  for (int i = tid; i < NBUK; i += 256) {
    lbase[i] = gh[(size_t)i * NBLK_BIN + blk];
    lcur[i] = 0;
  }
  __syncthreads();
  const int start = blk * CHUNK;
  const int end = (start + CHUNK < N_EDGES) ? start + CHUNK : N_EDGES;
  for (int e = start + tid; e < end; e += 256) {
    int r = row[e], c = col[e];
    int b = c >> 8;
    unsigned idx = atomicAdd(&lcur[b], 1u);
    binned[lbase[b] + idx] = (((unsigned)(c & 255)) << 17) | (unsigned)r;
  }
}

// ------- place (fused): bucket -> node offs + exact CSC (LDS hist+scan) ---
__global__ __launch_bounds__(256) void place_kernel(const unsigned* __restrict__ binned,
                                                    const unsigned* __restrict__ bbase2,
                                                    const unsigned* __restrict__ bhist,
                                                    unsigned* __restrict__ offs,
                                                    unsigned* __restrict__ rec4) {
  __shared__ unsigned lcnt[256];
  __shared__ unsigned lbase[256];
  __shared__ unsigned lcur[256];
  __shared__ unsigned wsum[4];
  __shared__ unsigned wbase[4];
  const int tid = threadIdx.x, lane = tid & 63, w = tid >> 6;
  const int b = blockIdx.x;
  const unsigned s = bbase2[b];
  const unsigned cnt = bhist[b];
  lcnt[tid] = 0;
  __syncthreads();
  for (unsigned i = tid; i < cnt; i += 256)
    atomicAdd(&lcnt[binned[s + i] >> 17], 1u);
  __syncthreads();
  unsigned v = lcnt[tid];
  unsigned inc = v;
  for (int d = 1; d < 64; d <<= 1) {
    unsigned x = (unsigned)__shfl_up((int)inc, d);
    if (lane >= d) inc += x;
  }
  if (lane == 63) wsum[w] = inc;
  __syncthreads();
  if (tid == 0) {
    unsigned run = 0;
    for (int j = 0; j < 4; ++j) { unsigned t = wsum[j]; wbase[j] = run; run += t; }
  }
  __syncthreads();
  unsigned ex = wbase[w] + inc - v;
  lbase[tid] = ex;
  lcur[tid] = 0;
  const int node = (b << 8) + tid;
  if (node < N_NODES) offs[node] = s + ex;
  if (b == 0 && tid == 0) offs[N_NODES] = N_EDGES;
  __syncthreads();
  for (unsigned i = tid; i < cnt; i += 256) {
    unsigned pv = binned[s + i];
    unsigned cI = pv >> 17;
    unsigned pos = atomicAdd(&lcur[cI], 1u);
    rec4[s + lbase[cI] + pos] = pv & 0x1FFFFu;
  }
}

// ------- W1 bf16 (nearest) in fragment-linear layout [t][n][g][8] --------
__global__ __launch_bounds__(256) void wprep1_kernel(const float* __restrict__ W1,
                                                     unsigned short* __restrict__ Whf) {
  int idx = blockIdx.x * 256 + threadIdx.x;
  if (idx >= HID_C * KPAD) return;
  int n = idx / KPAD, k = idx % KPAD;
  float v = (k < IN_C) ? W1[n * IN_C + k] : 0.f;
  int t = k >> 5, g = (k >> 3) & 3, j = k & 7;
  Whf[(size_t)t * 8192 + (((n << 2) + g) << 3) + j] = f2bf(v);
}

// ------- W2 hi/lo split, fragment-linear [ks][n(48)][g][8] ---------------
__global__ __launch_bounds__(256) void wprep2_kernel(const float* __restrict__ W2,
                                                     unsigned short* __restrict__ W2hf,
                                                     unsigned short* __restrict__ W2lf) {
  int idx = blockIdx.x * 256 + threadIdx.x;
  if (idx >= 48 * HID_C) return;
  int n = idx >> 8, k = idx & 255;
  float v = (n < OUTC) ? W2[n * HID_C + k] : 0.f;
  unsigned short hi = f2bf(v);
  int ks = k >> 5, g = (k >> 3) & 3, j = k & 7;
  size_t dst = (size_t)ks * 1536 + (((n << 2) + g) << 3) + j;
  W2hf[dst] = hi;
  W2lf[dst] = f2bf(v - bf2f(hi));
}

// ---------------- GEMM1: h1 = relu(x @ W1^T + b1), bf16 out --------------
__global__ __launch_bounds__(256, 3) void gemm1_kernel(
    const float* __restrict__ x,
    const unsigned short* __restrict__ Whf,
    const float* __restrict__ b1,
    unsigned short* __restrict__ h1g) {
  __shared__ __align__(16) float4 xt[3 * 512];        // 24 KB; reused as h1t
  unsigned short* h1t = (unsigned short*)xt;          // [32][264] in epilogue

  const int tid = threadIdx.x;
  const int lane = tid & 63;
  const int w = tid >> 6;
  const int r0 = blockIdx.x * 64;
  const int fr = lane & 15;
  const int g = lane >> 4;

  const int srow = tid >> 3;
  const int sc = tid & 7;
  int gr0 = r0 + srow;       if (gr0 >= N_NODES) gr0 = N_NODES - 1;
  int gr1 = r0 + srow + 32;  if (gr1 >= N_NODES) gr1 = N_NODES - 1;
  const float* xp0 = x + (size_t)gr0 * IN_C;
  const float* xp1 = x + (size_t)gr1 * IN_C;
  const int ws0 = srow * 8 + (sc ^ (srow & 7));
  const int ws1 = (srow + 32) * 8 + (sc ^ (srow & 7));

  f32x4 acc[4][4];
  {
    const int bcol0 = (w << 6) + fr;
#pragma unroll
    for (int s = 0; s < 4; ++s) {
      float bv = b1[bcol0 + s * 16];
#pragma unroll
      for (int mi = 0; mi < 4; ++mi) acc[mi][s] = (f32x4){bv, bv, bv, bv};
    }
  }

  float4 pA0, pA1, pB0, pB1;
  bf16x8 bhv[2][4];

#define STAGE_LOAD0(T)                                                     \
  { const int kb = (T) * 32 + sc * 4;                                      \
    if ((T) < NT - 1) { pA0 = *(const float4*)(xp0 + kb);                  \
                        pA1 = *(const float4*)(xp1 + kb); }                \
    else { float t0[4], t1[4];                                             \
      _Pragma("unroll") for (int j = 0; j < 4; ++j) { int k = kb + j;      \
        t0[j] = (k < IN_C) ? xp0[k] : 0.f; t1[j] = (k < IN_C) ? xp1[k] : 0.f; } \
      pA0 = (float4){t0[0], t0[1], t0[2], t0[3]};                          \
      pA1 = (float4){t1[0], t1[1], t1[2], t1[3]}; } }

#define STAGE_LOAD1(T)                                                     \
  { const int kb = (T) * 32 + sc * 4;                                      \
    if ((T) < NT - 1) { pB0 = *(const float4*)(xp0 + kb);                  \
                        pB1 = *(const float4*)(xp1 + kb); }                \
    else { float t0[4], t1[4];                                             \
      _Pragma("unroll") for (int j = 0; j < 4; ++j) { int k = kb + j;      \
        t0[j] = (k < IN_C) ? xp0[k] : 0.f; t1[j] = (k < IN_C) ? xp1[k] : 0.f; } \
      pB0 = (float4){t0[0], t0[1], t0[2], t0[3]};                          \
      pB1 = (float4){t1[0], t1[1], t1[2], t1[3]}; } }

#define STAGE_WRITE0(BW) { xt[(BW) * 512 + ws0] = pA0; xt[(BW) * 512 + ws1] = pA1; }
#define STAGE_WRITE1(BW) { xt[(BW) * 512 + ws0] = pB0; xt[(BW) * 512 + ws1] = pB1; }

#define LOADB(T, PAR)                                                      \
  { const size_t tb = (size_t)(T) * 8192;                                  \
    _Pragma("unroll") for (int s = 0; s < 4; ++s) {                        \
      const int n4 = (((w << 6) + s * 16 + fr) << 2) + g;                  \
      bhv[PAR][s] = *(const bf16x8*)(Whf + tb + n4 * 8);                   \
    } }

#define COMPUTE(BR, PAR)                                                   \
  { _Pragma("unroll") for (int mi = 0; mi < 4; ++mi) {                     \
      const int rr = mi * 16 + fr;                                         \
      float4 pa = xt[(BR) * 512 + rr * 8 + ((2 * g) ^ (fr & 7))];          \
      float4 pb = xt[(BR) * 512 + rr * 8 + ((2 * g + 1) ^ (fr & 7))];      \
      union { unsigned u[4]; bf16x8 v; } hh, ll;                           \
      asm("v_cvt_pk_bf16_f32 %0, %1, %2" : "=v"(hh.u[0]) : "v"(pa.x), "v"(pa.y)); \
      asm("v_cvt_pk_bf16_f32 %0, %1, %2" : "=v"(hh.u[1]) : "v"(pa.z), "v"(pa.w)); \
      asm("v_cvt_pk_bf16_f32 %0, %1, %2" : "=v"(hh.u[2]) : "v"(pb.x), "v"(pb.y)); \
      asm("v_cvt_pk_bf16_f32 %0, %1, %2" : "=v"(hh.u[3]) : "v"(pb.z), "v"(pb.w)); \
      float l0 = pa.x - bflo(hh.u[0]), l1 = pa.y - bfhi(hh.u[0]);          \
      float l2 = pa.z - bflo(hh.u[1]), l3 = pa.w - bfhi(hh.u[1]);          \
      float l4 = pb.x - bflo(hh.u[2]), l5 = pb.y - bfhi(hh.u[2]);          \
      float l6 = pb.z - bflo(hh.u[3]), l7 = pb.w - bfhi(hh.u[3]);          \
      asm("v_cvt_pk_bf16_f32 %0, %1, %2" : "=v"(ll.u[0]) : "v"(l0), "v"(l1)); \
      asm("v_cvt_pk_bf16_f32 %0, %1, %2" : "=v"(ll.u[1]) : "v"(l2), "v"(l3)); \
      asm("v_cvt_pk_bf16_f32 %0, %1, %2" : "=v"(ll.u[2]) : "v"(l4), "v"(l5)); \
      asm("v_cvt_pk_bf16_f32 %0, %1, %2" : "=v"(ll.u[3]) : "v"(l6), "v"(l7)); \
      _Pragma("unroll") for (int s = 0; s < 4; ++s) {                      \
        acc[mi][s] = __builtin_amdgcn_mfma_f32_16x16x32_bf16(              \
            hh.v, bhv[PAR][s], acc[mi][s], 0, 0, 0);                       \
        acc[mi][s] = __builtin_amdgcn_mfma_f32_16x16x32_bf16(              \
            ll.v, bhv[PAR][s], acc[mi][s], 0, 0, 0);                       \
      } } }

#define BODY(T, PAR)                                                       \
  { int bW = bR + 1; if (bW == 3) bW = 0;                                  \
    if ((T) + 1 < NT) {                                                    \
      if ((PAR) == 0) STAGE_WRITE1(bW) else STAGE_WRITE0(bW);              \
      if ((T) + 3 < NT) { if ((PAR) == 0) STAGE_LOAD1((T) + 3)             \
                          else STAGE_LOAD0((T) + 3); }                     \
      LOADB((T) + 1, (PAR) ^ 1);                                           \
    }                                                                      \
    COMPUTE(bR, PAR);                                                      \
    __syncthreads();                                                       \
    bR = bW; }

  STAGE_LOAD0(0);
  STAGE_WRITE0(0);
  STAGE_LOAD1(1);
  STAGE_LOAD0(2);
  LOADB(0, 0);
  __syncthreads();

  int bR = 0;
  for (int t = 0; t + 1 < NT; t += 2) {
    BODY(t, 0);
    BODY(t + 1, 1);
  }
  BODY(NT - 1, 0);  // NT odd: tail tile, parity 0

  // epilogue: coalesced h1 store via 2 LDS chunks of 32 rows
#pragma unroll
  for (int ch = 0; ch < 2; ++ch) {
#pragma unroll
    for (int mi2 = 0; mi2 < 2; ++mi2) {
      const int mi = ch * 2 + mi2;
#pragma unroll
      for (int s = 0; s < 4; ++s)
#pragma unroll
        for (int q = 0; q < 4; ++q) {
          int rr = mi2 * 16 + (g << 2) + q;
          int cc = (w << 6) + s * 16 + fr;
          h1t[rr * 264 + cc] = f2bf(fmaxf(acc[mi][s][q], 0.f));
        }
    }
    __syncthreads();
    {
      const int row = tid >> 3, seg = tid & 7;
      const int gr = r0 + ch * 32 + row;
      if (gr < N_NODES) {
        const uint4* src = (const uint4*)&h1t[row * 264 + seg * 32];
        uint4* dst = (uint4*)(h1g + (size_t)gr * 256 + seg * 32);
        dst[0] = src[0];
        dst[1] = src[1];
        dst[2] = src[2];
        dst[3] = src[3];
      }
    }
    __syncthreads();
  }
}

// ------- GEMM2 + L2 norm: H0 = normalize(h1 @ W2^T + b2), bf16 out -------
__global__ __launch_bounds__(256) void gemm2_kernel(
    const unsigned short* __restrict__ h1g,
    const unsigned short* __restrict__ W2hf,
    const unsigned short* __restrict__ W2lf,
    const float* __restrict__ b2,
    unsigned short* __restrict__ H0) {
  const int tid = threadIdx.x;
  const int lane = tid & 63;
  const int w = tid >> 6;
  const int fr = lane & 15;
  const int g = lane >> 4;
  const int wr0 = blockIdx.x * 64 + w * 16;

  f32x4 acc[3];
#pragma unroll
  for (int s = 0; s < 3; ++s) {
    int c = s * 16 + fr;
    float bv = (c < OUTC) ? b2[c] : 0.f;
    acc[s] = (f32x4){bv, bv, bv, bv};
  }

  int ar = wr0 + fr;
  if (ar >= N_NODES) ar = N_NODES - 1;
  const unsigned short* ap = h1g + (size_t)ar * 256 + g * 8;

#pragma unroll
  for (int ks = 0; ks < 8; ++ks) {
    bf16x8 a = *(const bf16x8*)(ap + ks * 32);
#pragma unroll
    for (int s = 0; s < 3; ++s) {
      const int n4 = (((s * 16 + fr) << 2) + g) << 3;
      bf16x8 bh = *(const bf16x8*)(W2hf + (size_t)ks * 1536 + n4);
      bf16x8 bl = *(const bf16x8*)(W2lf + (size_t)ks * 1536 + n4);
      acc[s] = __builtin_amdgcn_mfma_f32_16x16x32_bf16(a, bh, acc[s], 0, 0, 0);
      acc[s] = __builtin_amdgcn_mfma_f32_16x16x32_bf16(a, bl, acc[s], 0, 0, 0);
    }
  }

  float ps[4];
#pragma unroll
  for (int q = 0; q < 4; ++q)
    ps[q] = acc[0][q] * acc[0][q] + acc[1][q] * acc[1][q] + acc[2][q] * acc[2][q];
#pragma unroll
  for (int m = 1; m < 16; m <<= 1)
#pragma unroll
    for (int q = 0; q < 4; ++q) ps[q] += __shfl_xor(ps[q], m);

#pragma unroll
  for (int q = 0; q < 4; ++q) {
    const int gr = wr0 + (g << 2) + q;
    if (gr < N_NODES) {
      float rn = 1.f / fmaxf(sqrtf(ps[q]), 1e-12f);
#pragma unroll
      for (int s = 0; s < 3; ++s)
        H0[(size_t)gr * HSTR + s * 16 + fr] = f2bf(acc[s][q] * rn);
      H0[(size_t)gr * HSTR + 48 + fr] = 0;
    }
  }
}

// ------- bf16 H0 -> fp8 row with embedded dinv ---------------------------
// Row (16 uints): slots 0-9 = cols 0-39 fp8; slot 10 = (col40, 0,0,0);
// slot 11 = 0; slot 12 = fp32 dinv bits; slots 13-15 = 0.
__global__ __launch_bounds__(256) void cvt8_kernel(const unsigned* __restrict__ h0b,
                                                   const float* __restrict__ dinv,
                                                   unsigned* __restrict__ h0f) {
  int idx = blockIdx.x * 256 + threadIdx.x;
  if (idx >= N_NODES * 16) return;
  int n = idx >> 4, j = idx & 15;
  unsigned out = 0;
  if (j < 10) {
    unsigned a = h0b[(size_t)n * 32 + 2 * j];
    unsigned b = h0b[(size_t)n * 32 + 2 * j + 1];
    int pk = __builtin_amdgcn_cvt_pk_fp8_f32(bflo(a), bfhi(a), 0, false);
    pk = __builtin_amdgcn_cvt_pk_fp8_f32(bflo(b), bfhi(b), pk, true);
    out = (unsigned)pk;
  } else if (j == 10) {
    unsigned a = h0b[(size_t)n * 32 + 20];
    out = (unsigned)__builtin_amdgcn_cvt_pk_fp8_f32(bflo(a), 0.f, 0, false);
  } else if (j == 12) {
    out = __float_as_uint(dinv[n]);
  }
  h0f[idx] = out;
}

// ----- APPNP iteration: fp8 rows, 8 nodes/wave (uint2 gathers) -----------
__global__ __launch_bounds__(256) void prop_kernel(
    const unsigned* __restrict__ hsrc,   // fp8 rows, 16 uints/row
    const unsigned* __restrict__ h0b,    // bf16 H0, 32 uints/row
    unsigned* __restrict__ hdst,         // fp8 rows (when fout == nullptr)
    float* __restrict__ fout,            // non-null on last iteration
    const unsigned* __restrict__ rec4,   // CSC: source node per edge
    const unsigned* __restrict__ offs) { // N+1 entries
  const int lane = threadIdx.x & 63;
  const int wv = threadIdx.x >> 6;
  const int sub = lane & 7;            // uint2 index within 64-B row
  const int n = blockIdx.x * 32 + wv * 8 + (lane >> 3);
  if (n >= N_NODES) return;
  const int sf = (lane & 56) + 6;      // lane holding uint2 {12,13} (dinv in .x)
  const unsigned s = offs[n];
  const unsigned e = offs[n + 1];
  const uint2* hs = (const uint2*)hsrc;
  float a0 = 0.f, a1 = 0.f, a2 = 0.f, a3 = 0.f;
  float a4 = 0.f, a5 = 0.f, a6 = 0.f, a7 = 0.f;
  float c0 = 0.f, c1 = 0.f, c2 = 0.f, c3 = 0.f;
  float c4 = 0.f, c5 = 0.f, c6 = 0.f, c7 = 0.f;

#define ACCU(U, W, P)                                                     \
  { f32x2 L0 = __builtin_amdgcn_cvt_pk_f32_fp8((int)(U).x, false);        \
    f32x2 H0_ = __builtin_amdgcn_cvt_pk_f32_fp8((int)(U).x, true);        \
    f32x2 L1 = __builtin_amdgcn_cvt_pk_f32_fp8((int)(U).y, false);        \
    f32x2 H1_ = __builtin_amdgcn_cvt_pk_f32_fp8((int)(U).y, true);        \
    P##0 += L0.x * (W); P##1 += L0.y * (W);                               \
    P##2 += H0_.x * (W); P##3 += H0_.y * (W);                             \
    P##4 += L1.x * (W); P##5 += L1.y * (W);                               \
    P##6 += H1_.x * (W); P##7 += H1_.y * (W); }

  // self row (also provides dinv_n via shfl from uint slot 12)
  uint2 su = hs[(size_t)n * 8 + sub];
  float dn = __uint_as_float(__shfl((int)su.x, sf));

  unsigned i = s;
  for (; i + 8 <= e; i += 8) {
    unsigned r0 = rec4[i],     r1 = rec4[i + 1], r2 = rec4[i + 2], r3 = rec4[i + 3];
    unsigned r4 = rec4[i + 4], r5 = rec4[i + 5], r6 = rec4[i + 6], r7 = rec4[i + 7];
    uint2 u0 = hs[(size_t)r0 * 8 + sub];
    uint2 u1 = hs[(size_t)r1 * 8 + sub];
    uint2 u2 = hs[(size_t)r2 * 8 + sub];
    uint2 u3 = hs[(size_t)r3 * 8 + sub];
    uint2 u4 = hs[(size_t)r4 * 8 + sub];
    uint2 u5 = hs[(size_t)r5 * 8 + sub];
    uint2 u6 = hs[(size_t)r6 * 8 + sub];
    uint2 u7 = hs[(size_t)r7 * 8 + sub];
    float d0 = __uint_as_float(__shfl((int)u0.x, sf));
    float d1 = __uint_as_float(__shfl((int)u1.x, sf));
    float d2 = __uint_as_float(__shfl((int)u2.x, sf));
    float d3 = __uint_as_float(__shfl((int)u3.x, sf));
    float d4 = __uint_as_float(__shfl((int)u4.x, sf));
    float d5 = __uint_as_float(__shfl((int)u5.x, sf));
    float d6 = __uint_as_float(__shfl((int)u6.x, sf));
    float d7 = __uint_as_float(__shfl((int)u7.x, sf));
    ACCU(u0, d0, a);
    ACCU(u1, d1, c);
    ACCU(u2, d2, a);
    ACCU(u3, d3, c);
    ACCU(u4, d4, a);
    ACCU(u5, d5, c);
    ACCU(u6, d6, a);
    ACCU(u7, d7, c);
  }
  for (; i < e; ++i) {
    unsigned r = rec4[i];
    uint2 u = hs[(size_t)r * 8 + sub];
    float d = __uint_as_float(__shfl((int)u.x, sf));
    ACCU(u, d, a);
  }
  // self-loop: weight dinv_n (whole sum later scaled by dinv_n)
  ACCU(su, dn, a);

  uint4 hv = ((const uint4*)h0b)[(size_t)n * 8 + sub];
  const float sc9 = 0.9f * dn;
  float o0 = sc9 * (a0 + c0) + 0.1f * bflo(hv.x);
  float o1 = sc9 * (a1 + c1) + 0.1f * bfhi(hv.x);
  float o2 = sc9 * (a2 + c2) + 0.1f * bflo(hv.y);
  float o3 = sc9 * (a3 + c3) + 0.1f * bfhi(hv.y);
  float o4 = sc9 * (a4 + c4) + 0.1f * bflo(hv.z);
  float o5 = sc9 * (a5 + c5) + 0.1f * bfhi(hv.z);
  float o6 = sc9 * (a6 + c6) + 0.1f * bflo(hv.w);
  float o7 = sc9 * (a7 + c7) + 0.1f * bfhi(hv.w);
  if (fout) {
    int cb = 8 * sub;
    if (cb < OUTC)     fout[(size_t)n * OUTC + cb] = o0;
    if (cb + 1 < OUTC) fout[(size_t)n * OUTC + cb + 1] = o1;
    if (cb + 2 < OUTC) fout[(size_t)n * OUTC + cb + 2] = o2;
    if (cb + 3 < OUTC) fout[(size_t)n * OUTC + cb + 3] = o3;
    if (cb + 4 < OUTC) fout[(size_t)n * OUTC + cb + 4] = o4;
    if (cb + 5 < OUTC) fout[(size_t)n * OUTC + cb + 5] = o5;
    if (cb + 6 < OUTC) fout[(size_t)n * OUTC + cb + 6] = o6;
    if (cb + 7 < OUTC) fout[(size_t)n * OUTC + cb + 7] = o7;
  } else {
    uint2 ow = make_uint2(0u, 0u);
    if (sub < 5) {
      int p0 = __builtin_amdgcn_cvt_pk_fp8_f32(o0, o1, 0, false);
      p0 = __builtin_amdgcn_cvt_pk_fp8_f32(o2, o3, p0, true);
      int p1 = __builtin_amdgcn_cvt_pk_fp8_f32(o4, o5, 0, false);
      p1 = __builtin_amdgcn_cvt_pk_fp8_f32(o6, o7, p1, true);
      ow.x = (unsigned)p0;
      ow.y = (unsigned)p1;
    } else if (sub == 5) {
      ow.x = (unsigned)__builtin_amdgcn_cvt_pk_fp8_f32(o0, o1, 0, false);
    } else if (sub == 6) {
      ow.x = __float_as_uint(dn);
    }
    ((uint2*)hdst)[(size_t)n * 8 + sub] = ow;
  }
}

// ---------------- host ----------------
extern "C" void kernel_launch(void* const* d_in, const int* in_sizes, int n_in,
                              void* d_out, int out_size, void* d_ws, size_t ws_size,
                              hipStream_t stream) {
  const float* x  = (const float*)d_in[0];
  const int*   ei = (const int*)d_in[1];
  const float* W1 = (const float*)d_in[2];
  const float* b1 = (const float*)d_in[3];
  const float* W2 = (const float*)d_in[4];
  const float* b2 = (const float*)d_in[5];
  float* out = (float*)d_out;

  char* p = (char*)d_ws;
  auto alloc = [&](size_t bytes) {
    char* q = p;
    p += (bytes + 255) & ~(size_t)255;
    return q;
  };
  float*    dinv   = (float*)   alloc((size_t)N_NODES * 4);
  unsigned* offs   = (unsigned*)alloc(((size_t)N_NODES + 1) * 4);
  unsigned* bhist  = (unsigned*)alloc((NBUK + 1) * 4);
  unsigned* bbase2 = (unsigned*)alloc((NBUK + 1) * 4);
  unsigned* gh     = (unsigned*)alloc((size_t)NBUK * NBLK_BIN * 4);
  unsigned* binned = (unsigned*)alloc((size_t)N_EDGES * 4);
  unsigned* rec4   = (unsigned*)alloc((size_t)N_EDGES * 4);
  unsigned short* H0b = (unsigned short*)alloc((size_t)N_NODES * HSTR * 2);
  unsigned* H0f = (unsigned*)alloc((size_t)N_NODES * 16 * 4);
  unsigned* HA  = (unsigned*)alloc((size_t)N_NODES * 16 * 4);
  unsigned* HB  = (unsigned*)alloc((size_t)N_NODES * 16 * 4);
  unsigned short* h1g = (unsigned short*)alloc((size_t)N_NODES * HID_C * 2);
  unsigned short* Whf = (unsigned short*)alloc((size_t)NT * 8192 * 2);
  unsigned short* W2hf = (unsigned short*)alloc((size_t)8 * 1536 * 2);
  unsigned short* W2lf = (unsigned short*)alloc((size_t)8 * 1536 * 2);

  const int* row = ei;            // edge_index[0] : sources
  const int* col = ei + N_EDGES;  // edge_index[1] : targets

  // CSC build: binned two-phase, deterministic, no global contended atomics
  binA_kernel<<<NBLK_BIN, 256, 0, stream>>>(col, gh);
  binScan_kernel<<<1, 512, 0, stream>>>(gh, bbase2, bhist);
  binB_kernel<<<NBLK_BIN, 256, 0, stream>>>(row, col, gh, binned);
  place_kernel<<<NBUK, 256, 0, stream>>>(binned, bbase2, bhist, offs, rec4);
  dinv_kernel<<<(N_NODES + 255) / 256, 256, 0, stream>>>(offs, dinv);

  // MLP chain
  wprep1_kernel<<<(HID_C * KPAD + 255) / 256, 256, 0, stream>>>(W1, Whf);
  wprep2_kernel<<<(48 * HID_C + 255) / 256, 256, 0, stream>>>(W2, W2hf, W2lf);
  gemm1_kernel<<<(N_NODES + 63) / 64, 256, 0, stream>>>(x, Whf, b1, h1g);
  gemm2_kernel<<<(N_NODES + 63) / 64, 256, 0, stream>>>(h1g, W2hf, W2lf, b2, H0b);
  cvt8_kernel<<<(N_NODES * 16 + 255) / 256, 256, 0, stream>>>((const unsigned*)H0b, dinv, H0f);

  const unsigned* src = H0f;
  unsigned* bufs[2] = {HA, HB};
  for (int k = 0; k < K_ITERS; ++k) {
    bool last = (k == K_ITERS - 1);
    unsigned* dst = last ? nullptr : bufs[k & 1];
    float* fdst = last ? out : nullptr;
    prop_kernel<<<(N_NODES + 31) / 32, 256, 0, stream>>>(
        src, (const unsigned*)H0b, dst, fdst, rec4, offs);
    src = dst;
  }
}